// Round 2
// baseline (82.178 us; speedup 1.0000x reference)
//
#include <hip/hip_runtime.h>
#include <math.h>

// Problem dims (fixed by reference)
#define BDIM 2048
#define ODIM 256
#define IDIM 256

// Tiling
#define BT 32    // batch rows per block
#define OT 32    // output cols per block
#define JT 64    // j chunk staged in LDS
#define LSTR 66  // LDS row stride in float2 (pad +2: 16B-aligned rows, worst 2-way conflict = free)

// out[b,o] = IDIM + C * sum_j 1/(D - 2at*cos(phi0 + x[b,j] + p[o,j]))
//   C = (t^2-1)(1-a^2),  D = 1+(at)^2
// cos(x'+p) = cos x' cos p - sin x' sin p  =>
//   den = D + (-2at*cos x')*cos p + (2at*sin x')*sin p
// Margins precomputed once:  Am[b][j] = (-2at*cos(phi0+x), 2at*sin(phi0+x)),
//                            Pm[o][j] = (cos p, sin p)

__global__ __launch_bounds__(256)
void photonic_margins(const float* __restrict__ X, const float* __restrict__ P,
                      float2* __restrict__ Am, float2* __restrict__ Pm,
                      float phi0, float m2at, float p2at) {
    int i = blockIdx.x * 256 + threadIdx.x;   // grid covers exactly BDIM*IDIM + ODIM*IDIM
    if (i < BDIM * IDIM) {
        float s, c;
        __sincosf(phi0 + X[i], &s, &c);
        Am[i] = make_float2(m2at * c, p2at * s);
    } else {
        int k = i - BDIM * IDIM;              // < ODIM*IDIM by grid construction
        float s, c;
        __sincosf(P[k], &s, &c);
        Pm[k] = make_float2(c, s);
    }
}

__global__ __launch_bounds__(256, 2)
void photonic_main(const float2* __restrict__ Am,  // [BDIM][IDIM]
                   const float2* __restrict__ Pm,  // [ODIM][IDIM]
                   float* __restrict__ Out,        // [BDIM][ODIM]
                   float Dc, float Cnum) {
    __shared__ float2 As[BT][LSTR];
    __shared__ float2 Ps[OT][LSTR];

    const int tid = threadIdx.x;
    const int tx = tid & 15;        // o-group
    const int ty = tid >> 4;        // b-group (0..15)
    const int o0 = blockIdx.x * OT;
    const int b0 = blockIdx.y * BT;

    float acc00 = 0.f, acc01 = 0.f, acc10 = 0.f, acc11 = 0.f;

    for (int j0 = 0; j0 < IDIM; j0 += JT) {
        // ---- stage margins (pure copy, float4 = 2 float2 per thread-iter) ----
        #pragma unroll
        for (int it = 0; it < (BT * JT / 2) / 256; ++it) {   // 4 iters
            int e  = tid + 256 * it;
            int r  = e >> 5;                 // 32 float4 per row
            int c4 = e & 31;
            float4 v = *(const float4*)(Am + (size_t)(b0 + r) * IDIM + j0 + c4 * 2);
            *(float4*)&As[r][c4 * 2] = v;
        }
        #pragma unroll
        for (int it = 0; it < (OT * JT / 2) / 256; ++it) {   // 4 iters
            int e  = tid + 256 * it;
            int r  = e >> 5;
            int c4 = e & 31;
            float4 v = *(const float4*)(Pm + (size_t)(o0 + r) * IDIM + j0 + c4 * 2);
            *(float4*)&Ps[r][c4 * 2] = v;
        }
        __syncthreads();

        #pragma unroll 4
        for (int jj = 0; jj < JT; jj += 4) {
            // 2 jj per b128 read
            float4 a0a = *(const float4*)&As[ty     ][jj    ];
            float4 a0b = *(const float4*)&As[ty     ][jj + 2];
            float4 a1a = *(const float4*)&As[ty + 16][jj    ];
            float4 a1b = *(const float4*)&As[ty + 16][jj + 2];
            float4 q0a = *(const float4*)&Ps[tx     ][jj    ];
            float4 q0b = *(const float4*)&Ps[tx     ][jj + 2];
            float4 q1a = *(const float4*)&Ps[tx + 16][jj    ];
            float4 q1b = *(const float4*)&Ps[tx + 16][jj + 2];

            // quad-rcp: 1/d1+1/d2+1/d3+1/d4 = ((d1+d2)*d34 + (d3+d4)*d12) / (d12*d34)
            {
                float d1 = fmaf(a0a.x, q0a.x, fmaf(a0a.y, q0a.y, Dc));
                float d2 = fmaf(a0a.z, q0a.z, fmaf(a0a.w, q0a.w, Dc));
                float d3 = fmaf(a0b.x, q0b.x, fmaf(a0b.y, q0b.y, Dc));
                float d4 = fmaf(a0b.z, q0b.z, fmaf(a0b.w, q0b.w, Dc));
                float d12 = d1 * d2, d34 = d3 * d4;
                float n = fmaf(d1 + d2, d34, (d3 + d4) * d12);
                acc00 = fmaf(n, __builtin_amdgcn_rcpf(d12 * d34), acc00);
            }
            {
                float d1 = fmaf(a0a.x, q1a.x, fmaf(a0a.y, q1a.y, Dc));
                float d2 = fmaf(a0a.z, q1a.z, fmaf(a0a.w, q1a.w, Dc));
                float d3 = fmaf(a0b.x, q1b.x, fmaf(a0b.y, q1b.y, Dc));
                float d4 = fmaf(a0b.z, q1b.z, fmaf(a0b.w, q1b.w, Dc));
                float d12 = d1 * d2, d34 = d3 * d4;
                float n = fmaf(d1 + d2, d34, (d3 + d4) * d12);
                acc01 = fmaf(n, __builtin_amdgcn_rcpf(d12 * d34), acc01);
            }
            {
                float d1 = fmaf(a1a.x, q0a.x, fmaf(a1a.y, q0a.y, Dc));
                float d2 = fmaf(a1a.z, q0a.z, fmaf(a1a.w, q0a.w, Dc));
                float d3 = fmaf(a1b.x, q0b.x, fmaf(a1b.y, q0b.y, Dc));
                float d4 = fmaf(a1b.z, q0b.z, fmaf(a1b.w, q0b.w, Dc));
                float d12 = d1 * d2, d34 = d3 * d4;
                float n = fmaf(d1 + d2, d34, (d3 + d4) * d12);
                acc10 = fmaf(n, __builtin_amdgcn_rcpf(d12 * d34), acc10);
            }
            {
                float d1 = fmaf(a1a.x, q1a.x, fmaf(a1a.y, q1a.y, Dc));
                float d2 = fmaf(a1a.z, q1a.z, fmaf(a1a.w, q1a.w, Dc));
                float d3 = fmaf(a1b.x, q1b.x, fmaf(a1b.y, q1b.y, Dc));
                float d4 = fmaf(a1b.z, q1b.z, fmaf(a1b.w, q1b.w, Dc));
                float d12 = d1 * d2, d34 = d3 * d4;
                float n = fmaf(d1 + d2, d34, (d3 + d4) * d12);
                acc11 = fmaf(n, __builtin_amdgcn_rcpf(d12 * d34), acc11);
            }
        }
        __syncthreads();
    }

    const float base = (float)IDIM;
    Out[(size_t)(b0 + ty     ) * ODIM + (o0 + tx     )] = base + Cnum * acc00;
    Out[(size_t)(b0 + ty     ) * ODIM + (o0 + tx + 16)] = base + Cnum * acc01;
    Out[(size_t)(b0 + ty + 16) * ODIM + (o0 + tx     )] = base + Cnum * acc10;
    Out[(size_t)(b0 + ty + 16) * ODIM + (o0 + tx + 16)] = base + Cnum * acc11;
}

extern "C" void kernel_launch(void* const* d_in, const int* in_sizes, int n_in,
                              void* d_out, int out_size, void* d_ws, size_t ws_size,
                              hipStream_t stream) {
    const float* X = (const float*)d_in[0];   // input_matrix [2048,256] f32
    const float* P = (const float*)d_in[1];   // phase_offset [256,256] f32
    float* Out = (float*)d_out;               // [2048,256] f32

    // Workspace layout: Am = 2048*256 float2 (4 MB), Pm = 256*256 float2 (0.5 MB)
    float2* Am = (float2*)d_ws;
    float2* Pm = Am + (size_t)BDIM * IDIM;

    // Physics constants (double precision on host)
    const double RADIUS = 5e-6, KAPPA = 0.1, N_EFF = 3.48, LAMBDA = 1.55e-6, LOSS_A = 0.99;
    const double TWO_PI = 6.283185307179586476925286766559;
    const double t  = sqrt(1.0 - KAPPA);
    const double a  = LOSS_A;
    const double at = a * t;
    const double phi0 = fmod(TWO_PI * N_EFF * (TWO_PI * RADIUS) / LAMBDA, TWO_PI);
    const double D    = 1.0 + at * at;
    const double Cnum = (t * t - 1.0) * (1.0 - a * a);   // num - den (constant)

    // Kernel 1: margins (exactly covers BDIM*IDIM + ODIM*IDIM elements)
    int total = BDIM * IDIM + ODIM * IDIM;               // 589824 = 2304 * 256
    photonic_margins<<<total / 256, 256, 0, stream>>>(
        X, P, Am, Pm, (float)phi0, (float)(-2.0 * at), (float)(2.0 * at));

    // Kernel 2: main accumulation
    dim3 grid(ODIM / OT, BDIM / BT);  // 8 x 64 = 512 blocks
    photonic_main<<<grid, 256, 0, stream>>>(Am, Pm, Out, (float)D, (float)Cnum);
}